// Round 3
// baseline (145.984 us; speedup 1.0000x reference)
//
#include <hip/hip_runtime.h>
#include <math.h>

// SegmentTreeAttention — MI355X (gfx950), round 3.
// B=16, S=8192, D=64, N=32, LEVELS=5. f32 in/out. valid_lens per-batch.
//
// Round-2 was grid-limited: 1024 blocks = 4 blocks/CU = 16 waves/CU while
// VGPR=76 allows 6 waves/SIMD (24/CU). Changes:
//  - QPB 128 -> 64: grid 2048 blocks -> ~6 resident blocks/CU (24 waves/CU).
//  - Gather row indices packed 4-per-int (5 VGPRs instead of 20).
//  - __launch_bounds__(256, 6) regression guard.
// Numerics identical to the passing round-1/2 kernels: IEEE-div sigmoid
// 1/(1+__expf(-s)), subtract-then-dot segments, pow2 level scales.

#define SEG_N   32
#define DIM     64
#define LEVELS  5
#define QPB     64      // queries per block
#define THREADS 256
#define PAD     68      // LDS row stride in dwords

__device__ __forceinline__ float4 f4sub(const float4 a, const float4 b) {
    return make_float4(a.x - b.x, a.y - b.y, a.z - b.z, a.w - b.w);
}
__device__ __forceinline__ float4 sel4(bool c, const float4 a, const float4 b) {
    return make_float4(c ? a.x : b.x, c ? a.y : b.y, c ? a.z : b.z, c ? a.w : b.w);
}
__device__ __forceinline__ float dot4(const float4 a, const float4 b) {
    return a.x * b.x + a.y * b.y + a.z * b.z + a.w * b.w;
}
__device__ __forceinline__ void fma4(float4& acc, const float4 hi, const float4 lo, float w) {
    acc.x = fmaf(hi.x - lo.x, w, acc.x);
    acc.y = fmaf(hi.y - lo.y, w, acc.y);
    acc.z = fmaf(hi.z - lo.z, w, acc.z);
    acc.w = fmaf(hi.w - lo.w, w, acc.w);
}

__global__ __launch_bounds__(THREADS, 6) void segtree_attn_kernel(
    const float* __restrict__ q,
    const float* __restrict__ keys,
    const float* __restrict__ values,
    const int*   __restrict__ vlen,
    float*       __restrict__ out,
    int S)
{
    __shared__ float Pk[SEG_N * PAD];
    __shared__ float Pv[SEG_N * PAD];

    const int b = blockIdx.y;
    const int t = threadIdx.x;

    // ---- Stage prefix sums into LDS: P[0]=0, P[m]=sum_{l=1..m} x[l] ----
    if (t < 2 * DIM) {
        const int col = t & (DIM - 1);
        const float* src = ((t < DIM) ? keys : values) + (size_t)b * SEG_N * DIM + col;
        float* dst = (t < DIM) ? Pk : Pv;
        float acc = 0.0f;
        dst[col] = 0.0f;
        #pragma unroll
        for (int row = 1; row < SEG_N; ++row) {
            acc += src[row * DIM];
            dst[row * PAD + col] = acc;
        }
    }
    const int n = vlen[b];          // block-uniform (valid_lens is [B])
    __syncthreads();

    const int g = t >> 3;           // query group within block (0..31)
    const int u = t & 7;            // lane within group
    const int c = u * 8;            // column base (2x float4)

    const int hnc = max(min(n - 1, SEG_N - 1), 0);
    const float4 pkN0 = *(const float4*)&Pk[hnc * PAD + c];
    const float4 pkN1 = *(const float4*)&Pk[hnc * PAD + c + 4];

    const int sA = blockIdx.x * QPB + g;
    const int sB = sA + 32;
    const float scale[LEVELS] = {0.0625f, 0.125f, 0.25f, 0.5f, 1.0f};

    const float* qpA = q + ((size_t)b * S + sA) * DIM + c;
    const float* qpB = q + ((size_t)b * S + sB) * DIM + c;
    const float4 qA0 = *(const float4*)qpA;
    const float4 qA1 = *(const float4*)(qpA + 4);
    const float4 qB0 = *(const float4*)qpB;
    const float4 qB1 = *(const float4*)(qpB + 4);

    int lA = 1, rA = SEG_N, rowA_A = 0, rowR_A = hnc;
    int lB = 1, rB = SEG_N, rowA_B = 0, rowR_B = hnc;
    float4 pkA_A0 = make_float4(0.f,0.f,0.f,0.f), pkA_A1 = make_float4(0.f,0.f,0.f,0.f);
    float4 pkA_B0 = make_float4(0.f,0.f,0.f,0.f), pkA_B1 = make_float4(0.f,0.f,0.f,0.f);
    float4 pkR_A0 = pkN0, pkR_A1 = pkN1;
    float4 pkR_B0 = pkN0, pkR_B1 = pkN1;

    float wA[LEVELS], wB[LEVELS];
    int   rows[LEVELS];             // hiA | loA<<8 | hiB<<16 | loB<<24

    #pragma unroll
    for (int lev = 0; lev < LEVELS; ++lev) {
        const int midA = (lA + rA) >> 1;
        const int midB = (lB + rB) >> 1;

        const float4 pkM_A0 = *(const float4*)&Pk[midA * PAD + c];
        const float4 pkM_A1 = *(const float4*)&Pk[midA * PAD + c + 4];
        const float4 pkM_B0 = *(const float4*)&Pk[midB * PAD + c];
        const float4 pkM_B1 = *(const float4*)&Pk[midB * PAD + c + 4];

        const bool inLA = (midA <= n - 1);
        const bool inLB = (midB <= n - 1);
        const int rowHiL_A = inLA ? midA : hnc;
        const int rowHiL_B = inLB ? midB : hnc;
        const float4 pkHiL_A0 = sel4(inLA, pkM_A0, pkN0);
        const float4 pkHiL_A1 = sel4(inLA, pkM_A1, pkN1);
        const float4 pkHiL_B0 = sel4(inLB, pkM_B0, pkN0);
        const float4 pkHiL_B1 = sel4(inLB, pkM_B1, pkN1);

        // subtract-then-dot (matches reference rounding structure)
        float dLA = dot4(qA0, f4sub(pkHiL_A0, pkA_A0)) + dot4(qA1, f4sub(pkHiL_A1, pkA_A1));
        float dRA = dot4(qA0, f4sub(pkR_A0,  pkM_A0)) + dot4(qA1, f4sub(pkR_A1,  pkM_A1));
        float dLB = dot4(qB0, f4sub(pkHiL_B0, pkA_B0)) + dot4(qB1, f4sub(pkHiL_B1, pkA_B1));
        float dRB = dot4(qB0, f4sub(pkR_B0,  pkM_B0)) + dot4(qB1, f4sub(pkR_B1,  pkM_B1));

        #pragma unroll
        for (int m = 1; m < 8; m <<= 1) {
            dLA += __shfl_xor(dLA, m, 64);
            dRA += __shfl_xor(dRA, m, 64);
            dLB += __shfl_xor(dLB, m, 64);
            dRB += __shfl_xor(dRB, m, 64);
        }

        const bool okLA = (min(midA, n - 1) >= lA);
        const bool okRA = (min(rA,   n - 1) >= midA + 1);
        const bool okLB = (min(midB, n - 1) >= lB);
        const bool okRB = (min(rB,   n - 1) >= midB + 1);

        const float sLA = okLA ? dLA : 0.0f;
        const float sRA = okRA ? dRA : 0.0f;
        const float sLB = okLB ? dLB : 0.0f;
        const float sRB = okRB ? dRB : 0.0f;

        // exact formula from the passing round-1/2 kernels (IEEE div)
        const float lsA = 1.0f / (1.0f + __expf(-sLA));
        const float rsA = 1.0f / (1.0f + __expf(-sRA));
        const float lsB = 1.0f / (1.0f + __expf(-sLB));
        const float rsB = 1.0f / (1.0f + __expf(-sRB));

        const bool condA = (lsA >= rsA);
        const bool condB = (lsB >= rsB);

        const bool  okselA = condA ? okRA : okLA;
        const bool  okselB = condB ? okRB : okLB;
        const float wselA  = condA ? rsA : lsA;
        const float wselB  = condB ? rsB : lsB;
        wA[lev] = okselA ? (wselA * scale[lev]) : 0.0f;   // pow2 scale: exact
        wB[lev] = okselB ? (wselB * scale[lev]) : 0.0f;

        const int hiA = condA ? rowR_A : rowHiL_A;
        const int loA = condA ? midA   : rowA_A;
        const int hiB = condB ? rowR_B : rowHiL_B;
        const int loB = condB ? midB   : rowA_B;
        rows[lev] = hiA | (loA << 8) | (hiB << 16) | (loB << 24);

        if (condA) {
            rA = midA; rowR_A = rowHiL_A;
            pkR_A0 = pkHiL_A0; pkR_A1 = pkHiL_A1;
        } else {
            lA = midA + 1; rowA_A = midA;
            pkA_A0 = pkM_A0; pkA_A1 = pkM_A1;
        }
        if (condB) {
            rB = midB; rowR_B = rowHiL_B;
            pkR_B0 = pkHiL_B0; pkR_B1 = pkHiL_B1;
        } else {
            lB = midB + 1; rowA_B = midB;
            pkA_B0 = pkM_B0; pkA_B1 = pkM_B1;
        }
    }

    // ---- deferred value gather: ans = sum_lev w * (Pv[hi] - Pv[lo]) ----
    float4 aA0 = make_float4(0.f,0.f,0.f,0.f), aA1 = make_float4(0.f,0.f,0.f,0.f);
    float4 aB0 = make_float4(0.f,0.f,0.f,0.f), aB1 = make_float4(0.f,0.f,0.f,0.f);
    #pragma unroll
    for (int lev = 0; lev < LEVELS; ++lev) {
        const int pk = rows[lev];
        const int hiAr = pk & 0xFF, loAr = (pk >> 8) & 0xFF;
        const int hiBr = (pk >> 16) & 0xFF, loBr = (pk >> 24) & 0xFF;
        const float4 hA0 = *(const float4*)&Pv[hiAr * PAD + c];
        const float4 hA1 = *(const float4*)&Pv[hiAr * PAD + c + 4];
        const float4 lA0 = *(const float4*)&Pv[loAr * PAD + c];
        const float4 lA1 = *(const float4*)&Pv[loAr * PAD + c + 4];
        fma4(aA0, hA0, lA0, wA[lev]);
        fma4(aA1, hA1, lA1, wA[lev]);
        const float4 hB0 = *(const float4*)&Pv[hiBr * PAD + c];
        const float4 hB1 = *(const float4*)&Pv[hiBr * PAD + c + 4];
        const float4 lB0 = *(const float4*)&Pv[loBr * PAD + c];
        const float4 lB1 = *(const float4*)&Pv[loBr * PAD + c + 4];
        fma4(aB0, hB0, lB0, wB[lev]);
        fma4(aB1, hB1, lB1, wB[lev]);
    }

    float* opA = out + ((size_t)b * S + sA) * DIM + c;
    float* opB = out + ((size_t)b * S + sB) * DIM + c;
    *(float4*)opA       = aA0;
    *(float4*)(opA + 4) = aA1;
    *(float4*)opB       = aB0;
    *(float4*)(opB + 4) = aB1;
}

extern "C" void kernel_launch(void* const* d_in, const int* in_sizes, int n_in,
                              void* d_out, int out_size, void* d_ws, size_t ws_size,
                              hipStream_t stream) {
    const float* q    = (const float*)d_in[0];
    const float* keys = (const float*)d_in[1];
    const float* vals = (const float*)d_in[2];
    const int*   vl   = (const int*)d_in[3];
    float* out = (float*)d_out;

    const int B = in_sizes[3];                 // 16
    const int S = in_sizes[0] / (B * DIM);     // 8192

    dim3 grid(S / QPB, B);
    segtree_attn_kernel<<<grid, THREADS, 0, stream>>>(q, keys, vals, vl, out, S);
}

// Round 5
// 26.532 us; speedup vs baseline: 5.5021x; 5.5021x over previous
//
#include <hip/hip_runtime.h>
#include <math.h>

// SegmentTreeAttention — MI355X (gfx950), round 5.
// B=16, S=8192, D=64, N=32, LEVELS=5. f32 in/out. valid_lens per-batch.
//
// Round-4 failed to compile: __builtin_amdgcn_update_dpp needs an immediate
// dpp_ctrl -> moved to a template parameter. Otherwise identical plan:
//  - QPB=64 (2048 blocks, ~6 resident blocks/CU), no launch-bounds cap.
//  - 8-lane dot reduction via DPP (quad_perm xor1, xor2, row_half_mirror)
//    instead of 12 ds_swizzle shuffles per level: bit-identical summation
//    order, removes DS-pipe latency from the serial descent chain.
// Numerics identical to passing rounds 1-3: IEEE-div sigmoid
// 1/(1+__expf(-s)), subtract-then-dot segments, pow2 level scales.

#define SEG_N   32
#define DIM     64
#define LEVELS  5
#define QPB     64      // queries per block
#define THREADS 256
#define PAD     68      // LDS row stride in dwords

#define DPP_QUAD_XOR1   0xB1    // quad_perm [1,0,3,2]
#define DPP_QUAD_XOR2   0x4E    // quad_perm [2,3,0,1]
#define DPP_ROW_HMIRROR 0x141   // row_half_mirror (lane p -> 7-p within 8)

template <int CTRL>
__device__ __forceinline__ float dpp_xadd(float v) {
    const int s = __builtin_amdgcn_update_dpp(0, __float_as_int(v), CTRL, 0xf, 0xf, true);
    return v + __int_as_float(s);
}

// 8-lane group sum, all lanes get the bit-identical total.
__device__ __forceinline__ float group8_sum(float v) {
    v = dpp_xadd<DPP_QUAD_XOR1>(v);
    v = dpp_xadd<DPP_QUAD_XOR2>(v);
    v = dpp_xadd<DPP_ROW_HMIRROR>(v);   // add other quad's (uniform) quad-sum
    return v;
}

__device__ __forceinline__ float4 f4sub(const float4 a, const float4 b) {
    return make_float4(a.x - b.x, a.y - b.y, a.z - b.z, a.w - b.w);
}
__device__ __forceinline__ float4 sel4(bool c, const float4 a, const float4 b) {
    return make_float4(c ? a.x : b.x, c ? a.y : b.y, c ? a.z : b.z, c ? a.w : b.w);
}
__device__ __forceinline__ float dot4(const float4 a, const float4 b) {
    return a.x * b.x + a.y * b.y + a.z * b.z + a.w * b.w;
}
__device__ __forceinline__ void fma4(float4& acc, const float4 hi, const float4 lo, float w) {
    acc.x = fmaf(hi.x - lo.x, w, acc.x);
    acc.y = fmaf(hi.y - lo.y, w, acc.y);
    acc.z = fmaf(hi.z - lo.z, w, acc.z);
    acc.w = fmaf(hi.w - lo.w, w, acc.w);
}

__global__ __launch_bounds__(THREADS) void segtree_attn_kernel(
    const float* __restrict__ q,
    const float* __restrict__ keys,
    const float* __restrict__ values,
    const int*   __restrict__ vlen,
    float*       __restrict__ out,
    int S)
{
    __shared__ float Pk[SEG_N * PAD];
    __shared__ float Pv[SEG_N * PAD];

    const int b = blockIdx.y;
    const int t = threadIdx.x;

    // ---- Stage prefix sums into LDS: P[0]=0, P[m]=sum_{l=1..m} x[l] ----
    if (t < 2 * DIM) {
        const int col = t & (DIM - 1);
        const float* src = ((t < DIM) ? keys : values) + (size_t)b * SEG_N * DIM + col;
        float* dst = (t < DIM) ? Pk : Pv;
        float acc = 0.0f;
        dst[col] = 0.0f;
        #pragma unroll
        for (int row = 1; row < SEG_N; ++row) {
            acc += src[row * DIM];
            dst[row * PAD + col] = acc;
        }
    }
    const int n = vlen[b];          // block-uniform (valid_lens is [B])
    __syncthreads();

    const int g = t >> 3;           // query group within block (0..31)
    const int u = t & 7;            // lane within group
    const int c = u * 8;            // column base (2x float4)

    const int hnc = max(min(n - 1, SEG_N - 1), 0);
    const float4 pkN0 = *(const float4*)&Pk[hnc * PAD + c];
    const float4 pkN1 = *(const float4*)&Pk[hnc * PAD + c + 4];

    const int sA = blockIdx.x * QPB + g;
    const int sB = sA + 32;
    const float scale[LEVELS] = {0.0625f, 0.125f, 0.25f, 0.5f, 1.0f};

    const float* qpA = q + ((size_t)b * S + sA) * DIM + c;
    const float* qpB = q + ((size_t)b * S + sB) * DIM + c;
    const float4 qA0 = *(const float4*)qpA;
    const float4 qA1 = *(const float4*)(qpA + 4);
    const float4 qB0 = *(const float4*)qpB;
    const float4 qB1 = *(const float4*)(qpB + 4);

    int lA = 1, rA = SEG_N, rowA_A = 0, rowR_A = hnc;
    int lB = 1, rB = SEG_N, rowA_B = 0, rowR_B = hnc;
    float4 pkA_A0 = make_float4(0.f,0.f,0.f,0.f), pkA_A1 = make_float4(0.f,0.f,0.f,0.f);
    float4 pkA_B0 = make_float4(0.f,0.f,0.f,0.f), pkA_B1 = make_float4(0.f,0.f,0.f,0.f);
    float4 pkR_A0 = pkN0, pkR_A1 = pkN1;
    float4 pkR_B0 = pkN0, pkR_B1 = pkN1;

    float wA[LEVELS], wB[LEVELS];
    int   rows[LEVELS];             // hiA | loA<<8 | hiB<<16 | loB<<24

    #pragma unroll
    for (int lev = 0; lev < LEVELS; ++lev) {
        const int midA = (lA + rA) >> 1;
        const int midB = (lB + rB) >> 1;

        const float4 pkM_A0 = *(const float4*)&Pk[midA * PAD + c];
        const float4 pkM_A1 = *(const float4*)&Pk[midA * PAD + c + 4];
        const float4 pkM_B0 = *(const float4*)&Pk[midB * PAD + c];
        const float4 pkM_B1 = *(const float4*)&Pk[midB * PAD + c + 4];

        const bool inLA = (midA <= n - 1);
        const bool inLB = (midB <= n - 1);
        const int rowHiL_A = inLA ? midA : hnc;
        const int rowHiL_B = inLB ? midB : hnc;
        const float4 pkHiL_A0 = sel4(inLA, pkM_A0, pkN0);
        const float4 pkHiL_A1 = sel4(inLA, pkM_A1, pkN1);
        const float4 pkHiL_B0 = sel4(inLB, pkM_B0, pkN0);
        const float4 pkHiL_B1 = sel4(inLB, pkM_B1, pkN1);

        // subtract-then-dot (matches reference rounding structure)
        float dLA = dot4(qA0, f4sub(pkHiL_A0, pkA_A0)) + dot4(qA1, f4sub(pkHiL_A1, pkA_A1));
        float dRA = dot4(qA0, f4sub(pkR_A0,  pkM_A0)) + dot4(qA1, f4sub(pkR_A1,  pkM_A1));
        float dLB = dot4(qB0, f4sub(pkHiL_B0, pkA_B0)) + dot4(qB1, f4sub(pkHiL_B1, pkA_B1));
        float dRB = dot4(qB0, f4sub(pkR_B0,  pkM_B0)) + dot4(qB1, f4sub(pkR_B1,  pkM_B1));

        // 8-lane reduce, DPP only (bit-identical order to the xor butterfly)
        dLA = group8_sum(dLA);
        dRA = group8_sum(dRA);
        dLB = group8_sum(dLB);
        dRB = group8_sum(dRB);

        const bool okLA = (min(midA, n - 1) >= lA);
        const bool okRA = (min(rA,   n - 1) >= midA + 1);
        const bool okLB = (min(midB, n - 1) >= lB);
        const bool okRB = (min(rB,   n - 1) >= midB + 1);

        const float sLA = okLA ? dLA : 0.0f;
        const float sRA = okRA ? dRA : 0.0f;
        const float sLB = okLB ? dLB : 0.0f;
        const float sRB = okRB ? dRB : 0.0f;

        // exact formula from the passing rounds (IEEE div)
        const float lsA = 1.0f / (1.0f + __expf(-sLA));
        const float rsA = 1.0f / (1.0f + __expf(-sRA));
        const float lsB = 1.0f / (1.0f + __expf(-sLB));
        const float rsB = 1.0f / (1.0f + __expf(-sRB));

        const bool condA = (lsA >= rsA);
        const bool condB = (lsB >= rsB);

        const bool  okselA = condA ? okRA : okLA;
        const bool  okselB = condB ? okRB : okLB;
        const float wselA  = condA ? rsA : lsA;
        const float wselB  = condB ? rsB : lsB;
        wA[lev] = okselA ? (wselA * scale[lev]) : 0.0f;   // pow2 scale: exact
        wB[lev] = okselB ? (wselB * scale[lev]) : 0.0f;

        const int hiA = condA ? rowR_A : rowHiL_A;
        const int loA = condA ? midA   : rowA_A;
        const int hiB = condB ? rowR_B : rowHiL_B;
        const int loB = condB ? midB   : rowA_B;
        rows[lev] = hiA | (loA << 8) | (hiB << 16) | (loB << 24);

        if (condA) {
            rA = midA; rowR_A = rowHiL_A;
            pkR_A0 = pkHiL_A0; pkR_A1 = pkHiL_A1;
        } else {
            lA = midA + 1; rowA_A = midA;
            pkA_A0 = pkM_A0; pkA_A1 = pkM_A1;
        }
        if (condB) {
            rB = midB; rowR_B = rowHiL_B;
            pkR_B0 = pkHiL_B0; pkR_B1 = pkHiL_B1;
        } else {
            lB = midB + 1; rowA_B = midB;
            pkA_B0 = pkM_B0; pkA_B1 = pkM_B1;
        }
    }

    // ---- deferred value gather: ans = sum_lev w * (Pv[hi] - Pv[lo]) ----
    float4 aA0 = make_float4(0.f,0.f,0.f,0.f), aA1 = make_float4(0.f,0.f,0.f,0.f);
    float4 aB0 = make_float4(0.f,0.f,0.f,0.f), aB1 = make_float4(0.f,0.f,0.f,0.f);
    #pragma unroll
    for (int lev = 0; lev < LEVELS; ++lev) {
        const int pk = rows[lev];
        const int hiAr = pk & 0xFF, loAr = (pk >> 8) & 0xFF;
        const int hiBr = (pk >> 16) & 0xFF, loBr = (pk >> 24) & 0xFF;
        const float4 hA0 = *(const float4*)&Pv[hiAr * PAD + c];
        const float4 hA1 = *(const float4*)&Pv[hiAr * PAD + c + 4];
        const float4 lA0 = *(const float4*)&Pv[loAr * PAD + c];
        const float4 lA1 = *(const float4*)&Pv[loAr * PAD + c + 4];
        fma4(aA0, hA0, lA0, wA[lev]);
        fma4(aA1, hA1, lA1, wA[lev]);
        const float4 hB0 = *(const float4*)&Pv[hiBr * PAD + c];
        const float4 hB1 = *(const float4*)&Pv[hiBr * PAD + c + 4];
        const float4 lB0 = *(const float4*)&Pv[loBr * PAD + c];
        const float4 lB1 = *(const float4*)&Pv[loBr * PAD + c + 4];
        fma4(aB0, hB0, lB0, wB[lev]);
        fma4(aB1, hB1, lB1, wB[lev]);
    }

    float* opA = out + ((size_t)b * S + sA) * DIM + c;
    float* opB = out + ((size_t)b * S + sB) * DIM + c;
    *(float4*)opA       = aA0;
    *(float4*)(opA + 4) = aA1;
    *(float4*)opB       = aB0;
    *(float4*)(opB + 4) = aB1;
}

extern "C" void kernel_launch(void* const* d_in, const int* in_sizes, int n_in,
                              void* d_out, int out_size, void* d_ws, size_t ws_size,
                              hipStream_t stream) {
    const float* q    = (const float*)d_in[0];
    const float* keys = (const float*)d_in[1];
    const float* vals = (const float*)d_in[2];
    const int*   vl   = (const int*)d_in[3];
    float* out = (float*)d_out;

    const int B = in_sizes[3];                 // 16
    const int S = in_sizes[0] / (B * DIM);     // 8192

    dim3 grid(S / QPB, B);
    segtree_attn_kernel<<<grid, THREADS, 0, stream>>>(q, keys, vals, vl, out, S);
}